// Round 13
// baseline (155.244 us; speedup 1.0000x reference)
//
#include <hip/hip_runtime.h>
#include <hip/hip_bf16.h>
#include <math.h>

#define N_NODES  50000
#define N_FEAT   128
#define DIM      10
#define N_EDGES  1600000
#define N_GRAPHS 1000
#define PSTRIDE  16   // padded row stride for p / q (64B-aligned rows)
#define CAP      80   // adjacency capacity per node; deg ~ Poisson(32), P(>80)~5e-13
#define BSH      7    // bucket = dst >> 7 (128 nodes per bucket)
#define BNODES   128  // nodes per bucket
#define NBUCK    391  // ceil(50000/128)
#define ACHUNK   4096 // edges per binning block
#define ABLOCKS  ((N_EDGES + ACHUNK - 1) / ACHUNK)   // 391
#define PBLOCKS4 ((N_NODES * 4 + 255) / 256)         // 782 (4 threads per node)
#define CCAP     40   // per-(block,bucket) cell capacity; lambda=10.5, P(any overflow)~1.5e-6
#define SPLIT    2    // blocks per bucket in pull2B (thread-per-cell, ~196 cells each)
#define GSLOTS   128  // LDS graph-partial slots (128-node bucket spans ~3-4 graphs)
#define SENT     50000 // sentinel neighbor index -> zeroed pad row of p

// cell (k,b) = bedges[((size_t)k*NBUCK + b)*CCAP ...]; count in cellcnt[k*NBUCK+b].
// record = src:16 | nidx:7 (<<16)   (bucket implicit in cell address)

__device__ __forceinline__ float bf2f(unsigned short u) {
    union { unsigned int i; float f; } v;
    v.i = ((unsigned int)u) << 16;
    return v.f;
}

// generic float-array element load: fm=1 -> f32, fm=0 -> bf16
__device__ __forceinline__ float wload(const void* w, int fm, int i) {
    return fm ? ((const float*)w)[i] : bf2f(((const unsigned short*)w)[i]);
}

// int-array element load reading only the LOW 32 bits (values < 2^31):
// im=1 -> int64 (read low word), im=0 -> int32.
__device__ __forceinline__ int iload(const void* p, int im, long long pos) {
    return im ? ((const int*)p)[2 * pos] : ((const int*)p)[pos];
}

// Wave-ballot dtype probes: ONE load per lane, verdict wave-uniform by
// construction; ~zero register pressure (r8 lesson; r11/r12 verified).
__device__ __forceinline__ int probe_fm_w(const void* W1l) {
    const unsigned short* w = (const unsigned short*)W1l;
    int lane = threadIdx.x & 63;
    int expo = (w[lane] >> 7) & 0xFF;
    unsigned long long m = __ballot(expo >= 0x90);
    return (__popcll(m) >= 4) ? 1 : 0;
}
__device__ __forceinline__ int probe_im_w(const void* ei) {
    const unsigned int* e = (const unsigned int*)ei;
    int lane = threadIdx.x & 63;
    unsigned v = (lane < 8) ? e[2 * lane + 1] : 0u;
    unsigned long long m = __ballot(v != 0u);
    return (m == 0ull) ? 1 : 0;
}

#define ACCUM8(f0)                                                  \
    _Pragma("unroll")                                               \
    for (int d = 0; d < DIM; d++) {                                 \
        _Pragma("unroll")                                           \
        for (int k = 0; k < 8; k++) {                               \
            accl[d] += xf[k] * wl[d * N_FEAT + (f0) + k];           \
            accr[d] += xf[k] * wr[d * N_FEAT + (f0) + k];           \
        }                                                           \
    }

// Fused: blocks [0,ABLOCKS) bin edges into DETERMINISTIC per-(block,bucket)
// cells -- single-pass, 1.6KB LDS, NO global reservation atomics (r12's
// 153K device-scope bcur RMWs onto 61 cache lines are gone, along with the
// stage[] round-trip and 2 of 3 barriers). cellcnt is written (not
// accumulated) so no zeroing dispatch is needed at all.
// Blocks [ABLOCKS, +PBLOCKS4): p/q projections, 4 threads/node; the first
// projection block also zeroes gsum/gcnt and the sentinel p-row.
__global__ __launch_bounds__(256) void fusedA_kernel(
    const void* __restrict__ ei, const void* __restrict__ x,
    const void* __restrict__ W1l, const void* __restrict__ W1r,
    int* __restrict__ cellcnt, unsigned int* __restrict__ bedges,
    float* __restrict__ p, float* __restrict__ q,
    float* __restrict__ gsum, float* __restrict__ gcnt) {
    __shared__ union U {
        struct { int lcnt[NBUCK]; } a;                                // 1.6 KB
        struct { float wl[DIM * N_FEAT]; float wr[DIM * N_FEAT]; } b; // 10 KB
    } sh;

    if (blockIdx.x < ABLOCKS) {
        // ---- binning: single pass, direct cell placement ----
        int im = probe_im_w(ei);
        for (int b = threadIdx.x; b < NBUCK; b += 256) sh.a.lcnt[b] = 0;
        __syncthreads();
        long long e0 = (long long)blockIdx.x * ACHUNK;
        int nE = (int)min((long long)ACHUNK, (long long)N_EDGES - e0);
        size_t cellbase = (size_t)blockIdx.x * NBUCK;
        for (int i = threadIdx.x; i < nE; i += 256) {
            int s = iload(ei, im, e0 + i);
            int d = iload(ei, im, (long long)N_EDGES + e0 + i);
            int b = d >> BSH;
            unsigned rec = (unsigned)s | ((unsigned)(d & (BNODES - 1)) << 16);
            int pos = atomicAdd(&sh.a.lcnt[b], 1);
            if (pos < CCAP) bedges[(cellbase + b) * CCAP + pos] = rec;
        }
        __syncthreads();
        for (int b = threadIdx.x; b < NBUCK; b += 256)
            cellcnt[cellbase + b] = min(sh.a.lcnt[b], CCAP);
    } else {
        // ---- projection: p = W1_l @ x[n], q = W1_r @ x[n]; 4 threads per node ----
        int fm = probe_fm_w(W1l);
        if (blockIdx.x == ABLOCKS) {
            // zero accumulators (safe: pull2B is 2 dispatches later) + sentinel row
            for (int i = threadIdx.x; i < N_GRAPHS; i += 256) { gsum[i] = 0.f; gcnt[i] = 0.f; }
            if (threadIdx.x < PSTRIDE) p[(size_t)SENT * PSTRIDE + threadIdx.x] = 0.f;
        }
        float* wl = sh.b.wl;
        float* wr = sh.b.wr;
        for (int i = threadIdx.x; i < DIM * N_FEAT; i += 256) {
            wl[i] = wload(W1l, fm, i);
            wr[i] = wload(W1r, fm, i);
        }
        __syncthreads();
        int tid4 = (blockIdx.x - ABLOCKS) * 256 + threadIdx.x;
        int n = tid4 >> 2;
        int sub = tid4 & 3;          // feature-chunk lane: fb = j*4+sub
        if (n >= N_NODES) return;

        float accl[DIM], accr[DIM];
#pragma unroll
        for (int d = 0; d < DIM; d++) { accl[d] = 0.f; accr[d] = 0.f; }

        if (fm) {
            const float4* xr = reinterpret_cast<const float4*>((const float*)x + (size_t)n * N_FEAT);
#pragma unroll
            for (int j = 0; j < 4; j++) {
                int fb = j * 4 + sub;   // 8-float chunk index; LDS banks {0,8,16,24} across subs
                float4 v0 = xr[2 * fb];
                float4 v1 = xr[2 * fb + 1];
                float xf[8] = {v0.x, v0.y, v0.z, v0.w, v1.x, v1.y, v1.z, v1.w};
                ACCUM8(fb * 8)
            }
        } else {
            const uint4* xr = reinterpret_cast<const uint4*>((const unsigned short*)x + (size_t)n * N_FEAT);
#pragma unroll
            for (int j = 0; j < 4; j++) {
                int fb = j * 4 + sub;
                uint4 v = xr[fb];
                float xf[8];
                xf[0] = bf2f((unsigned short)(v.x & 0xffff)); xf[1] = bf2f((unsigned short)(v.x >> 16));
                xf[2] = bf2f((unsigned short)(v.y & 0xffff)); xf[3] = bf2f((unsigned short)(v.y >> 16));
                xf[4] = bf2f((unsigned short)(v.z & 0xffff)); xf[5] = bf2f((unsigned short)(v.z >> 16));
                xf[6] = bf2f((unsigned short)(v.w & 0xffff)); xf[7] = bf2f((unsigned short)(v.w >> 16));
                ACCUM8(fb * 8)
            }
        }
        // butterfly-reduce partials across the 4 sub-lanes (all lanes end with totals)
#pragma unroll
        for (int d = 0; d < DIM; d++) {
            accl[d] += __shfl_xor(accl[d], 1, 4);
            accl[d] += __shfl_xor(accl[d], 2, 4);
            accr[d] += __shfl_xor(accr[d], 1, 4);
            accr[d] += __shfl_xor(accr[d], 2, 4);
        }
        if (sub == 0) {
            float4* pr = reinterpret_cast<float4*>(p + (size_t)n * PSTRIDE);
            float4* qr = reinterpret_cast<float4*>(q + (size_t)n * PSTRIDE);
            pr[0] = make_float4(accl[0], accl[1], accl[2], accl[3]);
            pr[1] = make_float4(accl[4], accl[5], accl[6], accl[7]);
            pr[2] = make_float4(accl[8], accl[9], 0.f, 0.f);
            pr[3] = make_float4(0.f, 0.f, 0.f, 0.f);
            qr[0] = make_float4(accr[0], accr[1], accr[2], accr[3]);
            qr[1] = make_float4(accr[4], accr[5], accr[6], accr[7]);
            qr[2] = make_float4(accr[8], accr[9], 0.f, 0.f);
            qr[3] = make_float4(0.f, 0.f, 0.f, 0.f);
        }
    }
}

// Fused binB + pull1, 128-node buckets: 391 blocks x 512 threads, ~21KB LDS.
// Phase 1: thread-per-cell scatter of the bucket's 391 cells into LDS
// adjacency (lanes 0-15 meanwhile fold Wfc through W2 -> svl/svr);
// phase 2: layer-1 pull (4 threads/node), gathering p rows (L2/L3-resident).
__global__ __launch_bounds__(512) void pullB_kernel(
    const int* __restrict__ cellcnt, const unsigned int* __restrict__ bedges,
    const float* __restrict__ p, const float* __restrict__ q,
    const void* __restrict__ W1l, const void* __restrict__ W2l,
    const void* __restrict__ W2r, const void* __restrict__ Wfc,
    float* __restrict__ t, float* __restrict__ u, float* __restrict__ dinv) {
    __shared__ unsigned short lcol[BNODES * CAP];   // 20 KB
    __shared__ int lcnt[BNODES];
    __shared__ float svl[16], svr[16];
    int fm = probe_fm_w(W1l);
    if (threadIdx.x < 16) {
        float al = 0.f, ar = 0.f;
        if (threadIdx.x < DIM) {
            for (int i = 0; i < DIM; i++) {
                float w = wload(Wfc, fm, i);
                al += w * wload(W2l, fm, i * DIM + threadIdx.x);
                ar += w * wload(W2r, fm, i * DIM + threadIdx.x);
            }
        }
        svl[threadIdx.x] = al;
        svr[threadIdx.x] = ar;
    }
    // prefill with SENT so tail reads hit the zeroed pad row of p (no masking)
    const unsigned int s2 = (unsigned)SENT | ((unsigned)SENT << 16);
    uint4 sv = make_uint4(s2, s2, s2, s2);
    uint4* l4 = reinterpret_cast<uint4*>(lcol);
    for (int i = threadIdx.x; i < BNODES * CAP * 2 / 16; i += 512) l4[i] = sv;
    if (threadIdx.x < BNODES) lcnt[threadIdx.x] = 0;
    __syncthreads();

    int b = blockIdx.x;
    // thread-per-cell: cell (k, b) for k in [0, ABLOCKS)
    for (int k = threadIdx.x; k < ABLOCKS; k += 512) {
        int cnt = cellcnt[(size_t)k * NBUCK + b];
        const unsigned int* cell = bedges + ((size_t)k * NBUCK + b) * CCAP;
        for (int j = 0; j < cnt; j++) {
            unsigned rec = cell[j];
            int nidx = (rec >> 16) & (BNODES - 1);
            int pos = atomicAdd(&lcnt[nidx], 1);
            if (pos < CAP) lcol[nidx * CAP + pos] = (unsigned short)(rec & 0xffffu);
        }
    }
    __syncthreads();

    // ---- pull phase: 4 threads per node, adjacency straight from LDS ----
    int n = threadIdx.x >> 2;            // 0..127
    int sub4 = (threadIdx.x & 3) * 4;
    int g = (b << BSH) + n;
    if (g >= N_NODES) return;
    int deg = lcnt[n];
    int dcl = min(deg, CAP);
    const unsigned short* cl = lcol + n * CAP;   // 160B rows, 16B-aligned
    float ax = 0.f, ay = 0.f, az = 0.f, aw = 0.f;
    for (int k0 = 0; k0 < dcl; k0 += 8) {
        uint4 cv = *reinterpret_cast<const uint4*>(cl + k0);   // ds_read_b128
        unsigned c[8];
        c[0] = cv.x & 0xffff; c[1] = cv.x >> 16;
        c[2] = cv.y & 0xffff; c[3] = cv.y >> 16;
        c[4] = cv.z & 0xffff; c[5] = cv.z >> 16;
        c[6] = cv.w & 0xffff; c[7] = cv.w >> 16;
#pragma unroll
        for (int j = 0; j < 8; j++) {
            const float4 v = *reinterpret_cast<const float4*>(p + (size_t)c[j] * PSTRIDE + sub4);
            ax += v.x; ay += v.y; az += v.z; aw += v.w;
        }
    }
    float di = 1.0f / fmaxf((float)deg, 1.0f);
    float4 qv  = *reinterpret_cast<const float4*>(q + (size_t)g * PSTRIDE + sub4);
    float4 vlv = *reinterpret_cast<const float4*>(svl + sub4);   // padded to 16 with zeros
    float4 vrv = *reinterpret_cast<const float4*>(svr + sub4);
    float hx = fmaxf(ax * di + qv.x, 0.f);
    float hy = fmaxf(ay * di + qv.y, 0.f);
    float hz = fmaxf(az * di + qv.z, 0.f);
    float hw = fmaxf(aw * di + qv.w, 0.f);
    float tv = hx * vlv.x + hy * vlv.y + hz * vlv.z + hw * vlv.w;
    float uv = hx * vrv.x + hy * vrv.y + hz * vrv.z + hw * vrv.w;
    tv += __shfl_xor(tv, 1, 4); tv += __shfl_xor(tv, 2, 4);
    uv += __shfl_xor(uv, 1, 4); uv += __shfl_xor(uv, 2, 4);
    if ((threadIdx.x & 3) == 0) {
        t[g] = tv;
        u[g] = uv;
        dinv[g] = di;
    }
}

// Layer-2 + pooling from the cells. Per-record LDS atomics target 128
// per-NODE slots (~2 lanes/addr); dinv scaling + u/count + graph fold in a
// per-block epilogue. sum_splits(partialS[n]) * dinv[n] == S[n]*dinv[n].
__global__ __launch_bounds__(256) void pull2B_kernel(
    const int* __restrict__ cellcnt, const unsigned int* __restrict__ bedges,
    const float* __restrict__ t, const float* __restrict__ u,
    const float* __restrict__ dinv, const void* __restrict__ batch,
    const void* __restrict__ ei,
    float* __restrict__ gsum, float* __restrict__ gcnt) {
    __shared__ float lnode[BNODES];   // per-node partial S = sum t[src]
    __shared__ float ldinv[BNODES];
    __shared__ int   lb[BNODES];
    __shared__ float lgs[GSLOTS];
    __shared__ float lgc[GSLOTS];
    int im = probe_im_w(ei);
    int b = blockIdx.x / SPLIT;
    int s = blockIdx.x % SPLIT;
    int tid = threadIdx.x;
    int node0 = b << BSH;
    int nvalid = min(BNODES, N_NODES - node0);
    if (tid < BNODES) lnode[tid] = 0.f;
    if (tid < nvalid) {
        ldinv[tid] = dinv[node0 + tid];
        lb[tid] = iload(batch, im, node0 + tid);
    }
    if (tid < GSLOTS) { lgs[tid] = 0.f; lgc[tid] = 0.f; }
    __syncthreads();
    // thread-per-cell over this split's k-range
    int c0 = (ABLOCKS * s) / SPLIT, c1 = (ABLOCKS * (s + 1)) / SPLIT;
    for (int k = c0 + tid; k < c1; k += 256) {
        int cnt = cellcnt[(size_t)k * NBUCK + b];
        const unsigned int* cell = bedges + ((size_t)k * NBUCK + b) * CCAP;
        for (int j = 0; j < cnt; j++) {
            unsigned rec = cell[j];
            atomicAdd(&lnode[(rec >> 16) & (BNODES - 1)], t[rec & 0xffffu]);
        }
    }
    __syncthreads();
    // ---- epilogue: fold nodes -> graph slots (once per block, not per record) ----
    int g0 = lb[0];
    int rng = lb[nvalid - 1] - g0 + 1;   // batch sorted -> contiguous graph range
    bool useLDS = (rng <= GSLOTS);
    if (tid < nvalid) {
        float gv = lnode[tid] * ldinv[tid];
        if (s == 0) gv += u[node0 + tid];          // node term folded once
        int gg = lb[tid];
        if (useLDS) {
            atomicAdd(&lgs[gg - g0], gv);
            if (s == 0) atomicAdd(&lgc[gg - g0], 1.0f);
        } else {
            if (gv != 0.f) atomicAdd(gsum + gg, gv);
            if (s == 0) atomicAdd(gcnt + gg, 1.0f);
        }
    }
    __syncthreads();
    if (useLDS) {
        for (int i = tid; i < rng; i += 256) {
            float v = lgs[i];
            if (v != 0.f) atomicAdd(gsum + g0 + i, v);
            if (s == 0) {
                float c = lgc[i];
                if (c != 0.f) atomicAdd(gcnt + g0 + i, c);
            }
        }
    }
}

__global__ __launch_bounds__(256) void final_kernel(
    const float* __restrict__ gsum, const float* __restrict__ gcnt,
    const void* __restrict__ W1l, void* __restrict__ out) {
    int fm = probe_fm_w(W1l);
    int g = blockIdx.x * 256 + threadIdx.x;
    if (g >= N_GRAPHS) return;
    float pooled = gsum[g] / fmaxf(gcnt[g], 1.0f);
    float sg = 1.0f / (1.0f + expf(-pooled));
    if (fm) {
        ((float*)out)[g] = sg;
    } else {
        ((__hip_bfloat16*)out)[g] = __float2bfloat16(sg);
    }
}

extern "C" void kernel_launch(void* const* d_in, const int* in_sizes, int n_in,
                              void* d_out, int out_size, void* d_ws, size_t ws_size,
                              hipStream_t stream) {
    const void* x    = d_in[0];
    const void* W1l  = d_in[1];
    const void* W1r  = d_in[2];
    const void* W2l  = d_in[3];
    const void* W2r  = d_in[4];
    const void* Wfc  = d_in[5];
    const void* ei   = d_in[6];   // [2, E] flat: src then dst
    const void* batc = d_in[7];

    // ws is 256 MiB; ~28 MB used. NO zeroing dispatch: cellcnt is written (not
    // accumulated) by fusedA; gsum/gcnt zeroed by fusedA's first projection
    // block (2 dispatches before pull2B reads them). 4 dispatches total.
    char* ws = (char*)d_ws;
    int*   cellcnt = (int*)ws;                            // ABLOCKS*NBUCK (~611 KB)
    float* gsum = (float*)(cellcnt + (size_t)ABLOCKS * NBUCK);  // N_GRAPHS
    float* gcnt = gsum + N_GRAPHS;                        // N_GRAPHS
    unsigned int* bedges = (unsigned int*)(ws + ((((size_t)(gcnt + N_GRAPHS) - (size_t)ws) + 255) & ~(size_t)255));
    float* p    = (float*)(bedges + (size_t)ABLOCKS * NBUCK * CCAP);  // (N_NODES+1)*PSTRIDE
    float* q    = p + (size_t)(N_NODES + 1) * PSTRIDE;       // N_NODES*PSTRIDE
    float* t    = q + (size_t)N_NODES * PSTRIDE;             // N_NODES
    float* u    = t + N_NODES;                               // N_NODES
    float* dinv = u + N_NODES;                               // N_NODES

    fusedA_kernel<<<ABLOCKS + PBLOCKS4, 256, 0, stream>>>(
        ei, x, W1l, W1r, cellcnt, bedges, p, q, gsum, gcnt);
    pullB_kernel<<<NBUCK, 512, 0, stream>>>(cellcnt, bedges, p, q,
                                            W1l, W2l, W2r, Wfc, t, u, dinv);
    pull2B_kernel<<<NBUCK * SPLIT, 256, 0, stream>>>(cellcnt, bedges, t, u, dinv, batc, ei, gsum, gcnt);
    final_kernel<<<(N_GRAPHS + 255) / 256, 256, 0, stream>>>(gsum, gcnt, W1l, d_out);
}

// Round 14
// 149.582 us; speedup vs baseline: 1.0379x; 1.0379x over previous
//
#include <hip/hip_runtime.h>
#include <hip/hip_bf16.h>
#include <math.h>

#define N_NODES  50000
#define N_FEAT   128
#define DIM      10
#define N_EDGES  1600000
#define N_GRAPHS 1000
#define PSTRIDE  16   // padded row stride for p / q (64B-aligned rows)
#define CAP      80   // adjacency capacity per node; deg ~ Poisson(32), P(>80)~5e-13
#define BSH      7    // bucket = dst >> 7 (128 nodes per bucket)
#define BNODES   128  // nodes per bucket
#define NBUCK    391  // ceil(50000/128)
#define BCAP     4608 // per-bucket edge capacity; mean 4096, sd ~64 -> +8 sigma
#define ACHUNK   4096 // edges per phase-A block; union LDS ~19KB -> 8 blocks/CU
#define ABLOCKS  ((N_EDGES + ACHUNK - 1) / ACHUNK)   // 391
#define PBLOCKS4 ((N_NODES * 4 + 255) / 256)         // 782 (4 threads per node)
#define SPLIT    4    // blocks per bucket in pull2B -> 1564 blocks of ~1024 edges
#define GSLOTS   128  // LDS graph-partial slots (128-node bucket spans ~3-4 graphs)
#define SENT     50000 // sentinel neighbor index -> zeroed pad row of p

// record = src:16 | nidx:7 (<<16) | bucket:9 (<<23)

__device__ __forceinline__ float bf2f(unsigned short u) {
    union { unsigned int i; float f; } v;
    v.i = ((unsigned int)u) << 16;
    return v.f;
}

// generic float-array element load: fm=1 -> f32, fm=0 -> bf16
__device__ __forceinline__ float wload(const void* w, int fm, int i) {
    return fm ? ((const float*)w)[i] : bf2f(((const unsigned short*)w)[i]);
}

// int-array element load reading only the LOW 32 bits (values < 2^31):
// im=1 -> int64 (read low word), im=0 -> int32.
__device__ __forceinline__ int iload(const void* p, int im, long long pos) {
    return im ? ((const int*)p)[2 * pos] : ((const int*)p)[pos];
}

// Wave-ballot dtype probes: ONE load per lane, verdict wave-uniform by
// construction; ~zero register pressure (r8 lesson; r11/r12 verified).
__device__ __forceinline__ int probe_fm_w(const void* W1l) {
    const unsigned short* w = (const unsigned short*)W1l;
    int lane = threadIdx.x & 63;
    int expo = (w[lane] >> 7) & 0xFF;
    unsigned long long m = __ballot(expo >= 0x90);
    return (__popcll(m) >= 4) ? 1 : 0;
}
__device__ __forceinline__ int probe_im_w(const void* ei) {
    const unsigned int* e = (const unsigned int*)ei;
    int lane = threadIdx.x & 63;
    unsigned v = (lane < 8) ? e[2 * lane + 1] : 0u;
    unsigned long long m = __ballot(v != 0u);
    return (m == 0ull) ? 1 : 0;
}

#define ACCUM8(f0)                                                  \
    _Pragma("unroll")                                               \
    for (int d = 0; d < DIM; d++) {                                 \
        _Pragma("unroll")                                           \
        for (int k = 0; k < 8; k++) {                               \
            accl[d] += xf[k] * wl[d * N_FEAT + (f0) + k];           \
            accr[d] += xf[k] * wr[d * N_FEAT + (f0) + k];           \
        }                                                           \
    }

// Fused: blocks [0,ABLOCKS) bin edges into bucket segments. r14 CHANGE: the
// edge sweep loads 4 edges/thread via uint4 (dwordx4) -- int64 path was 2
// scalar stride-8 dword loads per edge (full lines dragged in anyway, ~2
// outstanding/wave -> fusedA ran at 1.16 TB/s, 5x below the fill kernels'
// 6.2 TB/s on identical hardware). Staged records written as ds_write_b128.
// Blocks [ABLOCKS, +PBLOCKS4): p/q projections, 4 threads/node.
__global__ __launch_bounds__(256) void fusedA_kernel(
    const void* __restrict__ ei, const void* __restrict__ x,
    const void* __restrict__ W1l, const void* __restrict__ W1r,
    int* __restrict__ bcur, unsigned int* __restrict__ bedges,
    float* __restrict__ p, float* __restrict__ q) {
    __shared__ union U {
        struct { unsigned int stage[ACHUNK]; int hcnt[NBUCK]; int hbase[NBUCK]; } a;  // ~19.1 KB
        struct { float wl[DIM * N_FEAT]; float wr[DIM * N_FEAT]; } b;                 // 10 KB
    } sh;

    if (blockIdx.x < ABLOCKS) {
        // ---- binning: record = src:16 | nidx:7 | bucket:9 ----
        int im = probe_im_w(ei);
        for (int b = threadIdx.x; b < NBUCK; b += 256) sh.a.hcnt[b] = 0;
        __syncthreads();
        long long e0 = (long long)blockIdx.x * ACHUNK;
        int nE = (int)min((long long)ACHUNK, (long long)N_EDGES - e0);
        int nB = nE >> 2;   // 4-edge batches; N_EDGES and ACHUNK divisible by 4
        if (im) {
            // int64 ids: 2 int64 per uint4 -> 2 loads for 4 src + 2 for 4 dst
            const uint4* s4 = reinterpret_cast<const uint4*>((const long long*)ei + e0);
            const uint4* d4 = reinterpret_cast<const uint4*>((const long long*)ei + N_EDGES + e0);
            for (int i = threadIdx.x; i < nB; i += 256) {
                uint4 sa = s4[2 * i], sb = s4[2 * i + 1];
                uint4 da = d4[2 * i], db = d4[2 * i + 1];
                unsigned ss[4] = {sa.x, sa.z, sb.x, sb.z};   // low words
                unsigned dd[4] = {da.x, da.z, db.x, db.z};
                unsigned r[4];
#pragma unroll
                for (int j = 0; j < 4; j++) {
                    int dj = (int)dd[j];
                    r[j] = ss[j] | ((unsigned)(dj & (BNODES - 1)) << 16) | ((unsigned)(dj >> BSH) << 23);
                    atomicAdd(&sh.a.hcnt[dj >> BSH], 1);
                }
                *reinterpret_cast<uint4*>(&sh.a.stage[4 * i]) = make_uint4(r[0], r[1], r[2], r[3]);
            }
        } else {
            const uint4* s4 = reinterpret_cast<const uint4*>((const int*)ei + e0);
            const uint4* d4 = reinterpret_cast<const uint4*>((const int*)ei + N_EDGES + e0);
            for (int i = threadIdx.x; i < nB; i += 256) {
                uint4 sa = s4[i];
                uint4 da = d4[i];
                unsigned ss[4] = {sa.x, sa.y, sa.z, sa.w};
                unsigned dd[4] = {da.x, da.y, da.z, da.w};
                unsigned r[4];
#pragma unroll
                for (int j = 0; j < 4; j++) {
                    int dj = (int)dd[j];
                    r[j] = ss[j] | ((unsigned)(dj & (BNODES - 1)) << 16) | ((unsigned)(dj >> BSH) << 23);
                    atomicAdd(&sh.a.hcnt[dj >> BSH], 1);
                }
                *reinterpret_cast<uint4*>(&sh.a.stage[4 * i]) = make_uint4(r[0], r[1], r[2], r[3]);
            }
        }
        __syncthreads();
        for (int b = threadIdx.x; b < NBUCK; b += 256) {
            int c = sh.a.hcnt[b];
            sh.a.hbase[b] = c ? atomicAdd(&bcur[b], c) : 0;
            sh.a.hcnt[b] = 0;   // reuse as local cursor
        }
        __syncthreads();
        for (int i = threadIdx.x; i < nE; i += 256) {
            unsigned rec = sh.a.stage[i];
            int b = rec >> 23;
            int pos = sh.a.hbase[b] + atomicAdd(&sh.a.hcnt[b], 1);
            if (pos < BCAP) bedges[(size_t)b * BCAP + pos] = rec;
        }
    } else {
        // ---- projection: p = W1_l @ x[n], q = W1_r @ x[n]; 4 threads per node ----
        int fm = probe_fm_w(W1l);
        // first projection block zeroes the sentinel row (done before pullB launches)
        if (blockIdx.x == ABLOCKS && threadIdx.x < PSTRIDE)
            p[(size_t)SENT * PSTRIDE + threadIdx.x] = 0.f;
        float* wl = sh.b.wl;
        float* wr = sh.b.wr;
        for (int i = threadIdx.x; i < DIM * N_FEAT; i += 256) {
            wl[i] = wload(W1l, fm, i);
            wr[i] = wload(W1r, fm, i);
        }
        __syncthreads();
        int tid4 = (blockIdx.x - ABLOCKS) * 256 + threadIdx.x;
        int n = tid4 >> 2;
        int sub = tid4 & 3;          // feature-chunk lane: fb = j*4+sub
        if (n >= N_NODES) return;

        float accl[DIM], accr[DIM];
#pragma unroll
        for (int d = 0; d < DIM; d++) { accl[d] = 0.f; accr[d] = 0.f; }

        if (fm) {
            const float4* xr = reinterpret_cast<const float4*>((const float*)x + (size_t)n * N_FEAT);
#pragma unroll
            for (int j = 0; j < 4; j++) {
                int fb = j * 4 + sub;   // 8-float chunk index; LDS banks {0,8,16,24} across subs
                float4 v0 = xr[2 * fb];
                float4 v1 = xr[2 * fb + 1];
                float xf[8] = {v0.x, v0.y, v0.z, v0.w, v1.x, v1.y, v1.z, v1.w};
                ACCUM8(fb * 8)
            }
        } else {
            const uint4* xr = reinterpret_cast<const uint4*>((const unsigned short*)x + (size_t)n * N_FEAT);
#pragma unroll
            for (int j = 0; j < 4; j++) {
                int fb = j * 4 + sub;
                uint4 v = xr[fb];
                float xf[8];
                xf[0] = bf2f((unsigned short)(v.x & 0xffff)); xf[1] = bf2f((unsigned short)(v.x >> 16));
                xf[2] = bf2f((unsigned short)(v.y & 0xffff)); xf[3] = bf2f((unsigned short)(v.y >> 16));
                xf[4] = bf2f((unsigned short)(v.z & 0xffff)); xf[5] = bf2f((unsigned short)(v.z >> 16));
                xf[6] = bf2f((unsigned short)(v.w & 0xffff)); xf[7] = bf2f((unsigned short)(v.w >> 16));
                ACCUM8(fb * 8)
            }
        }
        // butterfly-reduce partials across the 4 sub-lanes (all lanes end with totals)
#pragma unroll
        for (int d = 0; d < DIM; d++) {
            accl[d] += __shfl_xor(accl[d], 1, 4);
            accl[d] += __shfl_xor(accl[d], 2, 4);
            accr[d] += __shfl_xor(accr[d], 1, 4);
            accr[d] += __shfl_xor(accr[d], 2, 4);
        }
        if (sub == 0) {
            float4* pr = reinterpret_cast<float4*>(p + (size_t)n * PSTRIDE);
            float4* qr = reinterpret_cast<float4*>(q + (size_t)n * PSTRIDE);
            pr[0] = make_float4(accl[0], accl[1], accl[2], accl[3]);
            pr[1] = make_float4(accl[4], accl[5], accl[6], accl[7]);
            pr[2] = make_float4(accl[8], accl[9], 0.f, 0.f);
            pr[3] = make_float4(0.f, 0.f, 0.f, 0.f);
            qr[0] = make_float4(accr[0], accr[1], accr[2], accr[3]);
            qr[1] = make_float4(accr[4], accr[5], accr[6], accr[7]);
            qr[2] = make_float4(accr[8], accr[9], 0.f, 0.f);
            qr[3] = make_float4(0.f, 0.f, 0.f, 0.f);
        }
    }
}

// Fused binB + pull1, 128-node buckets: 391 blocks x 512 threads, ~21KB LDS.
// Phase 1 scatters the bucket's edge segment into LDS adjacency (lanes 0-15
// meanwhile fold Wfc through W2 -> svl/svr); phase 2 pulls layer-1
// (4 threads/node), gathering p rows (L2/L3-resident).
__global__ __launch_bounds__(512) void pullB_kernel(
    const int* __restrict__ bcur, const unsigned int* __restrict__ bedges,
    const float* __restrict__ p, const float* __restrict__ q,
    const void* __restrict__ W1l, const void* __restrict__ W2l,
    const void* __restrict__ W2r, const void* __restrict__ Wfc,
    float* __restrict__ t, float* __restrict__ u, float* __restrict__ dinv) {
    __shared__ unsigned short lcol[BNODES * CAP];   // 20 KB
    __shared__ int lcnt[BNODES];
    __shared__ float svl[16], svr[16];
    int fm = probe_fm_w(W1l);
    if (threadIdx.x < 16) {
        float al = 0.f, ar = 0.f;
        if (threadIdx.x < DIM) {
            for (int i = 0; i < DIM; i++) {
                float w = wload(Wfc, fm, i);
                al += w * wload(W2l, fm, i * DIM + threadIdx.x);
                ar += w * wload(W2r, fm, i * DIM + threadIdx.x);
            }
        }
        svl[threadIdx.x] = al;
        svr[threadIdx.x] = ar;
    }
    // prefill with SENT so tail reads hit the zeroed pad row of p (no masking)
    const unsigned int s2 = (unsigned)SENT | ((unsigned)SENT << 16);
    uint4 sv = make_uint4(s2, s2, s2, s2);
    uint4* l4 = reinterpret_cast<uint4*>(lcol);
    for (int i = threadIdx.x; i < BNODES * CAP * 2 / 16; i += 512) l4[i] = sv;
    if (threadIdx.x < BNODES) lcnt[threadIdx.x] = 0;
    __syncthreads();

    int b = blockIdx.x;
    int m = min(bcur[b], BCAP);
    const unsigned int* seg = bedges + (size_t)b * BCAP;
    for (int i = threadIdx.x; i < m; i += 512) {
        unsigned rec = seg[i];
        int nidx = (rec >> 16) & (BNODES - 1);
        int pos = atomicAdd(&lcnt[nidx], 1);
        if (pos < CAP) lcol[nidx * CAP + pos] = (unsigned short)(rec & 0xffffu);
    }
    __syncthreads();

    // ---- pull phase: 4 threads per node, adjacency straight from LDS ----
    int n = threadIdx.x >> 2;            // 0..127
    int sub4 = (threadIdx.x & 3) * 4;
    int g = (b << BSH) + n;
    if (g >= N_NODES) return;
    int deg = lcnt[n];
    int dcl = min(deg, CAP);
    const unsigned short* cl = lcol + n * CAP;   // 160B rows, 16B-aligned
    float ax = 0.f, ay = 0.f, az = 0.f, aw = 0.f;
    for (int k0 = 0; k0 < dcl; k0 += 8) {
        uint4 cv = *reinterpret_cast<const uint4*>(cl + k0);   // ds_read_b128
        unsigned c[8];
        c[0] = cv.x & 0xffff; c[1] = cv.x >> 16;
        c[2] = cv.y & 0xffff; c[3] = cv.y >> 16;
        c[4] = cv.z & 0xffff; c[5] = cv.z >> 16;
        c[6] = cv.w & 0xffff; c[7] = cv.w >> 16;
#pragma unroll
        for (int j = 0; j < 8; j++) {
            const float4 v = *reinterpret_cast<const float4*>(p + (size_t)c[j] * PSTRIDE + sub4);
            ax += v.x; ay += v.y; az += v.z; aw += v.w;
        }
    }
    float di = 1.0f / fmaxf((float)deg, 1.0f);
    float4 qv  = *reinterpret_cast<const float4*>(q + (size_t)g * PSTRIDE + sub4);
    float4 vlv = *reinterpret_cast<const float4*>(svl + sub4);   // padded to 16 with zeros
    float4 vrv = *reinterpret_cast<const float4*>(svr + sub4);
    float hx = fmaxf(ax * di + qv.x, 0.f);
    float hy = fmaxf(ay * di + qv.y, 0.f);
    float hz = fmaxf(az * di + qv.z, 0.f);
    float hw = fmaxf(aw * di + qv.w, 0.f);
    float tv = hx * vlv.x + hy * vlv.y + hz * vlv.z + hw * vlv.w;
    float uv = hx * vrv.x + hy * vrv.y + hz * vrv.z + hw * vrv.w;
    tv += __shfl_xor(tv, 1, 4); tv += __shfl_xor(tv, 2, 4);
    uv += __shfl_xor(uv, 1, 4); uv += __shfl_xor(uv, 2, 4);
    if ((threadIdx.x & 3) == 0) {
        t[g] = tv;
        u[g] = uv;
        dinv[g] = di;
    }
}

// Layer-2 + pooling from the bedges STREAM. Per-record LDS atomics target 128
// per-NODE slots (~2 lanes/addr); dinv scaling + u/count + graph fold in a
// per-block epilogue. sum_splits(partialS[n]) * dinv[n] == S[n]*dinv[n].
__global__ __launch_bounds__(256) void pull2B_kernel(
    const int* __restrict__ bcur, const unsigned int* __restrict__ bedges,
    const float* __restrict__ t, const float* __restrict__ u,
    const float* __restrict__ dinv, const void* __restrict__ batch,
    const void* __restrict__ ei,
    float* __restrict__ gsum, float* __restrict__ gcnt) {
    __shared__ float lnode[BNODES];   // per-node partial S = sum t[src]
    __shared__ float ldinv[BNODES];
    __shared__ int   lb[BNODES];
    __shared__ float lgs[GSLOTS];
    __shared__ float lgc[GSLOTS];
    int im = probe_im_w(ei);
    int b = blockIdx.x / SPLIT;
    int s = blockIdx.x % SPLIT;
    int tid = threadIdx.x;
    int node0 = b << BSH;
    int nvalid = min(BNODES, N_NODES - node0);
    if (tid < BNODES) lnode[tid] = 0.f;
    if (tid < nvalid) {
        ldinv[tid] = dinv[node0 + tid];
        lb[tid] = iload(batch, im, node0 + tid);
    }
    if (tid < GSLOTS) { lgs[tid] = 0.f; lgc[tid] = 0.f; }
    __syncthreads();
    int m = min(bcur[b], BCAP);
    int c0 = (m * s) / SPLIT, c1 = (m * (s + 1)) / SPLIT;
    const unsigned int* seg = bedges + (size_t)b * BCAP;
    for (int i = c0 + tid; i < c1; i += 256) {
        unsigned rec = seg[i];
        int src  = rec & 0xffffu;
        int nidx = (rec >> 16) & (BNODES - 1);
        atomicAdd(&lnode[nidx], t[src]);   // 128 slots: ~2 lanes/bank, near-free
    }
    __syncthreads();
    // ---- epilogue: fold nodes -> graph slots (once per block, not per record) ----
    int g0 = lb[0];
    int rng = lb[nvalid - 1] - g0 + 1;   // batch sorted -> contiguous graph range
    bool useLDS = (rng <= GSLOTS);
    if (tid < nvalid) {
        float gv = lnode[tid] * ldinv[tid];
        if (s == 0) gv += u[node0 + tid];          // node term folded once
        int gg = lb[tid];
        if (useLDS) {
            atomicAdd(&lgs[gg - g0], gv);
            if (s == 0) atomicAdd(&lgc[gg - g0], 1.0f);
        } else {
            if (gv != 0.f) atomicAdd(gsum + gg, gv);
            if (s == 0) atomicAdd(gcnt + gg, 1.0f);
        }
    }
    __syncthreads();
    if (useLDS) {
        for (int i = tid; i < rng; i += 256) {
            float v = lgs[i];
            if (v != 0.f) atomicAdd(gsum + g0 + i, v);
            if (s == 0) {
                float c = lgc[i];
                if (c != 0.f) atomicAdd(gcnt + g0 + i, c);
            }
        }
    }
}

__global__ __launch_bounds__(256) void final_kernel(
    const float* __restrict__ gsum, const float* __restrict__ gcnt,
    const void* __restrict__ W1l, void* __restrict__ out) {
    int fm = probe_fm_w(W1l);
    int g = blockIdx.x * 256 + threadIdx.x;
    if (g >= N_GRAPHS) return;
    float pooled = gsum[g] / fmaxf(gcnt[g], 1.0f);
    float sg = 1.0f / (1.0f + expf(-pooled));
    if (fm) {
        ((float*)out)[g] = sg;
    } else {
        ((__hip_bfloat16*)out)[g] = __float2bfloat16(sg);
    }
}

extern "C" void kernel_launch(void* const* d_in, const int* in_sizes, int n_in,
                              void* d_out, int out_size, void* d_ws, size_t ws_size,
                              hipStream_t stream) {
    const void* x    = d_in[0];
    const void* W1l  = d_in[1];
    const void* W1r  = d_in[2];
    const void* W2l  = d_in[3];
    const void* W2r  = d_in[4];
    const void* Wfc  = d_in[5];
    const void* ei   = d_in[6];   // [2, E] flat: src then dst
    const void* batc = d_in[7];

    // ws is 256 MiB; ~12 MB used. {bcur,gsum,gcnt} contiguous -> one small
    // memset replaces the serial detect/zero kernel (probes moved in-kernel).
    char* ws = (char*)d_ws;
    int*   bcur = (int*)ws;                               // NBUCK
    float* gsum = (float*)(bcur + NBUCK);                 // N_GRAPHS
    float* gcnt = gsum + N_GRAPHS;                        // N_GRAPHS
    unsigned int* bedges = (unsigned int*)(ws + ((((size_t)(gcnt + N_GRAPHS) - (size_t)ws) + 255) & ~(size_t)255));
    float* p    = (float*)(bedges + (size_t)NBUCK * BCAP);   // (N_NODES+1)*PSTRIDE (+1: sentinel row)
    float* q    = p + (size_t)(N_NODES + 1) * PSTRIDE;       // N_NODES*PSTRIDE
    float* t    = q + (size_t)N_NODES * PSTRIDE;             // N_NODES
    float* u    = t + N_NODES;                               // N_NODES
    float* dinv = u + N_NODES;                               // N_NODES

    hipMemsetAsync(bcur, 0, (NBUCK + 2 * N_GRAPHS) * sizeof(int), stream);
    fusedA_kernel<<<ABLOCKS + PBLOCKS4, 256, 0, stream>>>(
        ei, x, W1l, W1r, bcur, bedges, p, q);
    pullB_kernel<<<NBUCK, 512, 0, stream>>>(bcur, bedges, p, q,
                                            W1l, W2l, W2r, Wfc, t, u, dinv);
    pull2B_kernel<<<NBUCK * SPLIT, 256, 0, stream>>>(bcur, bedges, t, u, dinv, batc, ei, gsum, gcnt);
    final_kernel<<<(N_GRAPHS + 255) / 256, 256, 0, stream>>>(gsum, gcnt, W1l, d_out);
}

// Round 15
// 148.789 us; speedup vs baseline: 1.0434x; 1.0053x over previous
//
#include <hip/hip_runtime.h>
#include <hip/hip_bf16.h>
#include <math.h>

#define N_NODES  50000
#define N_FEAT   128
#define DIM      10
#define N_EDGES  1600000
#define N_GRAPHS 1000
#define PSTRIDE  16   // padded row stride for p / q (64B-aligned rows)
#define CAP      80   // adjacency capacity per node; deg ~ Poisson(32), P(>80)~5e-13
#define BSH      7    // bucket = dst >> 7 (128 nodes per bucket)
#define BNODES   128  // nodes per bucket
#define NBUCK    391  // ceil(50000/128)
#define BCAP     4608 // per-bucket edge capacity; mean 4096, sd ~64 -> +8 sigma
#define ACHUNK   4096 // edges per phase-A block; union LDS ~19KB -> 8 blocks/CU
#define ABLOCKS  ((N_EDGES + ACHUNK - 1) / ACHUNK)   // 391
#define PBLOCKS4 ((N_NODES * 4 + 255) / 256)         // 782 (4 threads per node)
#define SPLIT    4    // blocks per bucket in pull2B -> 1564 blocks of ~1024 edges
#define GSLOTS   128  // LDS graph-partial slots (128-node bucket spans ~3-4 graphs)
#define SENT     50000 // sentinel neighbor index -> zeroed pad row of p

// record = src:16 | nidx:7 (<<16) | bucket:9 (<<23)

__device__ __forceinline__ float bf2f(unsigned short u) {
    union { unsigned int i; float f; } v;
    v.i = ((unsigned int)u) << 16;
    return v.f;
}

// generic float-array element load: fm=1 -> f32, fm=0 -> bf16
__device__ __forceinline__ float wload(const void* w, int fm, int i) {
    return fm ? ((const float*)w)[i] : bf2f(((const unsigned short*)w)[i]);
}

// int-array element load reading only the LOW 32 bits (values < 2^31):
// im=1 -> int64 (read low word), im=0 -> int32.
__device__ __forceinline__ int iload(const void* p, int im, long long pos) {
    return im ? ((const int*)p)[2 * pos] : ((const int*)p)[pos];
}

// Wave-ballot dtype probes: ONE load per lane, verdict wave-uniform by
// construction; ~zero register pressure (r8 lesson; r11/r12 verified).
__device__ __forceinline__ int probe_fm_w(const void* W1l) {
    const unsigned short* w = (const unsigned short*)W1l;
    int lane = threadIdx.x & 63;
    int expo = (w[lane] >> 7) & 0xFF;
    unsigned long long m = __ballot(expo >= 0x90);
    return (__popcll(m) >= 4) ? 1 : 0;
}
__device__ __forceinline__ int probe_im_w(const void* ei) {
    const unsigned int* e = (const unsigned int*)ei;
    int lane = threadIdx.x & 63;
    unsigned v = (lane < 8) ? e[2 * lane + 1] : 0u;
    unsigned long long m = __ballot(v != 0u);
    return (m == 0ull) ? 1 : 0;
}

#define ACCUM8(f0)                                                  \
    _Pragma("unroll")                                               \
    for (int d = 0; d < DIM; d++) {                                 \
        _Pragma("unroll")                                           \
        for (int k = 0; k < 8; k++) {                               \
            accl[d] += xf[k] * wl[d * N_FEAT + (f0) + k];           \
            accr[d] += xf[k] * wr[d * N_FEAT + (f0) + k];           \
        }                                                           \
    }

// Fused: blocks [0,ABLOCKS) bin edges into bucket segments. r14: edge sweep
// loads 4 edges/thread via uint4 (validated +5us: MLP was the limiter).
// Blocks [ABLOCKS, +PBLOCKS4): p/q projections, 4 threads/node.
__global__ __launch_bounds__(256) void fusedA_kernel(
    const void* __restrict__ ei, const void* __restrict__ x,
    const void* __restrict__ W1l, const void* __restrict__ W1r,
    int* __restrict__ bcur, unsigned int* __restrict__ bedges,
    float* __restrict__ p, float* __restrict__ q) {
    __shared__ union U {
        struct { unsigned int stage[ACHUNK]; int hcnt[NBUCK]; int hbase[NBUCK]; } a;  // ~19.1 KB
        struct { float wl[DIM * N_FEAT]; float wr[DIM * N_FEAT]; } b;                 // 10 KB
    } sh;

    if (blockIdx.x < ABLOCKS) {
        // ---- binning: record = src:16 | nidx:7 | bucket:9 ----
        int im = probe_im_w(ei);
        for (int b = threadIdx.x; b < NBUCK; b += 256) sh.a.hcnt[b] = 0;
        __syncthreads();
        long long e0 = (long long)blockIdx.x * ACHUNK;
        int nE = (int)min((long long)ACHUNK, (long long)N_EDGES - e0);
        int nB = nE >> 2;   // 4-edge batches; N_EDGES and ACHUNK divisible by 4
        if (im) {
            // int64 ids: 2 int64 per uint4 -> 2 loads for 4 src + 2 for 4 dst
            const uint4* s4 = reinterpret_cast<const uint4*>((const long long*)ei + e0);
            const uint4* d4 = reinterpret_cast<const uint4*>((const long long*)ei + N_EDGES + e0);
            for (int i = threadIdx.x; i < nB; i += 256) {
                uint4 sa = s4[2 * i], sb = s4[2 * i + 1];
                uint4 da = d4[2 * i], db = d4[2 * i + 1];
                unsigned ss[4] = {sa.x, sa.z, sb.x, sb.z};   // low words
                unsigned dd[4] = {da.x, da.z, db.x, db.z};
                unsigned r[4];
#pragma unroll
                for (int j = 0; j < 4; j++) {
                    int dj = (int)dd[j];
                    r[j] = ss[j] | ((unsigned)(dj & (BNODES - 1)) << 16) | ((unsigned)(dj >> BSH) << 23);
                    atomicAdd(&sh.a.hcnt[dj >> BSH], 1);
                }
                *reinterpret_cast<uint4*>(&sh.a.stage[4 * i]) = make_uint4(r[0], r[1], r[2], r[3]);
            }
        } else {
            const uint4* s4 = reinterpret_cast<const uint4*>((const int*)ei + e0);
            const uint4* d4 = reinterpret_cast<const uint4*>((const int*)ei + N_EDGES + e0);
            for (int i = threadIdx.x; i < nB; i += 256) {
                uint4 sa = s4[i];
                uint4 da = d4[i];
                unsigned ss[4] = {sa.x, sa.y, sa.z, sa.w};
                unsigned dd[4] = {da.x, da.y, da.z, da.w};
                unsigned r[4];
#pragma unroll
                for (int j = 0; j < 4; j++) {
                    int dj = (int)dd[j];
                    r[j] = ss[j] | ((unsigned)(dj & (BNODES - 1)) << 16) | ((unsigned)(dj >> BSH) << 23);
                    atomicAdd(&sh.a.hcnt[dj >> BSH], 1);
                }
                *reinterpret_cast<uint4*>(&sh.a.stage[4 * i]) = make_uint4(r[0], r[1], r[2], r[3]);
            }
        }
        __syncthreads();
        for (int b = threadIdx.x; b < NBUCK; b += 256) {
            int c = sh.a.hcnt[b];
            sh.a.hbase[b] = c ? atomicAdd(&bcur[b], c) : 0;
            sh.a.hcnt[b] = 0;   // reuse as local cursor
        }
        __syncthreads();
        for (int i = threadIdx.x; i < nE; i += 256) {
            unsigned rec = sh.a.stage[i];
            int b = rec >> 23;
            int pos = sh.a.hbase[b] + atomicAdd(&sh.a.hcnt[b], 1);
            if (pos < BCAP) bedges[(size_t)b * BCAP + pos] = rec;
        }
    } else {
        // ---- projection: p = W1_l @ x[n], q = W1_r @ x[n]; 4 threads per node ----
        int fm = probe_fm_w(W1l);
        // first projection block zeroes the sentinel row (done before pullB launches)
        if (blockIdx.x == ABLOCKS && threadIdx.x < PSTRIDE)
            p[(size_t)SENT * PSTRIDE + threadIdx.x] = 0.f;
        float* wl = sh.b.wl;
        float* wr = sh.b.wr;
        for (int i = threadIdx.x; i < DIM * N_FEAT; i += 256) {
            wl[i] = wload(W1l, fm, i);
            wr[i] = wload(W1r, fm, i);
        }
        __syncthreads();
        int tid4 = (blockIdx.x - ABLOCKS) * 256 + threadIdx.x;
        int n = tid4 >> 2;
        int sub = tid4 & 3;          // feature-chunk lane: fb = j*4+sub
        if (n >= N_NODES) return;

        float accl[DIM], accr[DIM];
#pragma unroll
        for (int d = 0; d < DIM; d++) { accl[d] = 0.f; accr[d] = 0.f; }

        if (fm) {
            const float4* xr = reinterpret_cast<const float4*>((const float*)x + (size_t)n * N_FEAT);
#pragma unroll
            for (int j = 0; j < 4; j++) {
                int fb = j * 4 + sub;   // 8-float chunk index; LDS banks {0,8,16,24} across subs
                float4 v0 = xr[2 * fb];
                float4 v1 = xr[2 * fb + 1];
                float xf[8] = {v0.x, v0.y, v0.z, v0.w, v1.x, v1.y, v1.z, v1.w};
                ACCUM8(fb * 8)
            }
        } else {
            const uint4* xr = reinterpret_cast<const uint4*>((const unsigned short*)x + (size_t)n * N_FEAT);
#pragma unroll
            for (int j = 0; j < 4; j++) {
                int fb = j * 4 + sub;
                uint4 v = xr[fb];
                float xf[8];
                xf[0] = bf2f((unsigned short)(v.x & 0xffff)); xf[1] = bf2f((unsigned short)(v.x >> 16));
                xf[2] = bf2f((unsigned short)(v.y & 0xffff)); xf[3] = bf2f((unsigned short)(v.y >> 16));
                xf[4] = bf2f((unsigned short)(v.z & 0xffff)); xf[5] = bf2f((unsigned short)(v.z >> 16));
                xf[6] = bf2f((unsigned short)(v.w & 0xffff)); xf[7] = bf2f((unsigned short)(v.w >> 16));
                ACCUM8(fb * 8)
            }
        }
        // butterfly-reduce partials across the 4 sub-lanes (all lanes end with totals)
#pragma unroll
        for (int d = 0; d < DIM; d++) {
            accl[d] += __shfl_xor(accl[d], 1, 4);
            accl[d] += __shfl_xor(accl[d], 2, 4);
            accr[d] += __shfl_xor(accr[d], 1, 4);
            accr[d] += __shfl_xor(accr[d], 2, 4);
        }
        if (sub == 0) {
            float4* pr = reinterpret_cast<float4*>(p + (size_t)n * PSTRIDE);
            float4* qr = reinterpret_cast<float4*>(q + (size_t)n * PSTRIDE);
            pr[0] = make_float4(accl[0], accl[1], accl[2], accl[3]);
            pr[1] = make_float4(accl[4], accl[5], accl[6], accl[7]);
            pr[2] = make_float4(accl[8], accl[9], 0.f, 0.f);
            pr[3] = make_float4(0.f, 0.f, 0.f, 0.f);
            qr[0] = make_float4(accr[0], accr[1], accr[2], accr[3]);
            qr[1] = make_float4(accr[4], accr[5], accr[6], accr[7]);
            qr[2] = make_float4(accr[8], accr[9], 0.f, 0.f);
            qr[3] = make_float4(0.f, 0.f, 0.f, 0.f);
        }
    }
}

// Fused binB + pull1, 128-node buckets: 391 blocks x 512 threads, ~21KB LDS.
// r15: scatter phase reads records 4-at-a-time via uint4 (r14's validated
// MLP lever applied here): 4 independent LDS-atomic+store chains in flight.
__global__ __launch_bounds__(512) void pullB_kernel(
    const int* __restrict__ bcur, const unsigned int* __restrict__ bedges,
    const float* __restrict__ p, const float* __restrict__ q,
    const void* __restrict__ W1l, const void* __restrict__ W2l,
    const void* __restrict__ W2r, const void* __restrict__ Wfc,
    float* __restrict__ t, float* __restrict__ u, float* __restrict__ dinv) {
    __shared__ unsigned short lcol[BNODES * CAP];   // 20 KB
    __shared__ int lcnt[BNODES];
    __shared__ float svl[16], svr[16];
    int fm = probe_fm_w(W1l);
    if (threadIdx.x < 16) {
        float al = 0.f, ar = 0.f;
        if (threadIdx.x < DIM) {
            for (int i = 0; i < DIM; i++) {
                float w = wload(Wfc, fm, i);
                al += w * wload(W2l, fm, i * DIM + threadIdx.x);
                ar += w * wload(W2r, fm, i * DIM + threadIdx.x);
            }
        }
        svl[threadIdx.x] = al;
        svr[threadIdx.x] = ar;
    }
    // prefill with SENT so tail reads hit the zeroed pad row of p (no masking)
    const unsigned int s2 = (unsigned)SENT | ((unsigned)SENT << 16);
    uint4 sv = make_uint4(s2, s2, s2, s2);
    uint4* l4 = reinterpret_cast<uint4*>(lcol);
    for (int i = threadIdx.x; i < BNODES * CAP * 2 / 16; i += 512) l4[i] = sv;
    if (threadIdx.x < BNODES) lcnt[threadIdx.x] = 0;
    __syncthreads();

    int b = blockIdx.x;
    int m = min(bcur[b], BCAP);
    const unsigned int* seg = bedges + (size_t)b * BCAP;   // 16B-aligned (BCAP*4 % 16 == 0)
    int md = m & ~3;
    for (int i = 4 * (int)threadIdx.x; i < md; i += 4 * 512) {
        uint4 rv = *reinterpret_cast<const uint4*>(seg + i);
        unsigned r[4] = {rv.x, rv.y, rv.z, rv.w};
#pragma unroll
        for (int j = 0; j < 4; j++) {
            int nidx = (r[j] >> 16) & (BNODES - 1);
            int pos = atomicAdd(&lcnt[nidx], 1);
            if (pos < CAP) lcol[nidx * CAP + pos] = (unsigned short)(r[j] & 0xffffu);
        }
    }
    for (int i = md + threadIdx.x; i < m; i += 512) {
        unsigned rec = seg[i];
        int nidx = (rec >> 16) & (BNODES - 1);
        int pos = atomicAdd(&lcnt[nidx], 1);
        if (pos < CAP) lcol[nidx * CAP + pos] = (unsigned short)(rec & 0xffffu);
    }
    __syncthreads();

    // ---- pull phase: 4 threads per node, adjacency straight from LDS ----
    int n = threadIdx.x >> 2;            // 0..127
    int sub4 = (threadIdx.x & 3) * 4;
    int g = (b << BSH) + n;
    if (g >= N_NODES) return;
    int deg = lcnt[n];
    int dcl = min(deg, CAP);
    const unsigned short* cl = lcol + n * CAP;   // 160B rows, 16B-aligned
    float ax = 0.f, ay = 0.f, az = 0.f, aw = 0.f;
    for (int k0 = 0; k0 < dcl; k0 += 8) {
        uint4 cv = *reinterpret_cast<const uint4*>(cl + k0);   // ds_read_b128
        unsigned c[8];
        c[0] = cv.x & 0xffff; c[1] = cv.x >> 16;
        c[2] = cv.y & 0xffff; c[3] = cv.y >> 16;
        c[4] = cv.z & 0xffff; c[5] = cv.z >> 16;
        c[6] = cv.w & 0xffff; c[7] = cv.w >> 16;
#pragma unroll
        for (int j = 0; j < 8; j++) {
            const float4 v = *reinterpret_cast<const float4*>(p + (size_t)c[j] * PSTRIDE + sub4);
            ax += v.x; ay += v.y; az += v.z; aw += v.w;
        }
    }
    float di = 1.0f / fmaxf((float)deg, 1.0f);
    float4 qv  = *reinterpret_cast<const float4*>(q + (size_t)g * PSTRIDE + sub4);
    float4 vlv = *reinterpret_cast<const float4*>(svl + sub4);   // padded to 16 with zeros
    float4 vrv = *reinterpret_cast<const float4*>(svr + sub4);
    float hx = fmaxf(ax * di + qv.x, 0.f);
    float hy = fmaxf(ay * di + qv.y, 0.f);
    float hz = fmaxf(az * di + qv.z, 0.f);
    float hw = fmaxf(aw * di + qv.w, 0.f);
    float tv = hx * vlv.x + hy * vlv.y + hz * vlv.z + hw * vlv.w;
    float uv = hx * vrv.x + hy * vrv.y + hz * vrv.z + hw * vrv.w;
    tv += __shfl_xor(tv, 1, 4); tv += __shfl_xor(tv, 2, 4);
    uv += __shfl_xor(uv, 1, 4); uv += __shfl_xor(uv, 2, 4);
    if ((threadIdx.x & 3) == 0) {
        t[g] = tv;
        u[g] = uv;
        dinv[g] = di;
    }
}

// Layer-2 + pooling from the bedges STREAM. r15: records read 4-at-a-time via
// uint4, then 4 independent t[src] gathers in flight (was 1 serial chain per
// iteration -- gather-latency-bound). Per-record LDS atomics target 128
// per-NODE slots; dinv scaling + u/count + graph fold in a per-block epilogue.
__global__ __launch_bounds__(256) void pull2B_kernel(
    const int* __restrict__ bcur, const unsigned int* __restrict__ bedges,
    const float* __restrict__ t, const float* __restrict__ u,
    const float* __restrict__ dinv, const void* __restrict__ batch,
    const void* __restrict__ ei,
    float* __restrict__ gsum, float* __restrict__ gcnt) {
    __shared__ float lnode[BNODES];   // per-node partial S = sum t[src]
    __shared__ float ldinv[BNODES];
    __shared__ int   lb[BNODES];
    __shared__ float lgs[GSLOTS];
    __shared__ float lgc[GSLOTS];
    int im = probe_im_w(ei);
    int b = blockIdx.x / SPLIT;
    int s = blockIdx.x % SPLIT;
    int tid = threadIdx.x;
    int node0 = b << BSH;
    int nvalid = min(BNODES, N_NODES - node0);
    if (tid < BNODES) lnode[tid] = 0.f;
    if (tid < nvalid) {
        ldinv[tid] = dinv[node0 + tid];
        lb[tid] = iload(batch, im, node0 + tid);
    }
    if (tid < GSLOTS) { lgs[tid] = 0.f; lgc[tid] = 0.f; }
    __syncthreads();
    int m = min(bcur[b], BCAP);
    // 4-aligned split boundaries (consistent across s -> exact partition of [0,m))
    int c0 = ((m * s) / SPLIT) & ~3;
    int c1 = (s == SPLIT - 1) ? m : ((m * (s + 1)) / SPLIT) & ~3;
    const unsigned int* seg = bedges + (size_t)b * BCAP;   // 16B-aligned
    int c1d = c0 + ((c1 - c0) & ~3);
    for (int i = c0 + 4 * tid; i < c1d; i += 4 * 256) {
        uint4 rv = *reinterpret_cast<const uint4*>(seg + i);
        // 4 independent gathers issued back-to-back (ILP=4)
        float t0 = t[rv.x & 0xffffu];
        float t1 = t[rv.y & 0xffffu];
        float t2 = t[rv.z & 0xffffu];
        float t3 = t[rv.w & 0xffffu];
        atomicAdd(&lnode[(rv.x >> 16) & (BNODES - 1)], t0);
        atomicAdd(&lnode[(rv.y >> 16) & (BNODES - 1)], t1);
        atomicAdd(&lnode[(rv.z >> 16) & (BNODES - 1)], t2);
        atomicAdd(&lnode[(rv.w >> 16) & (BNODES - 1)], t3);
    }
    for (int i = c1d + tid; i < c1; i += 256) {
        unsigned rec = seg[i];
        atomicAdd(&lnode[(rec >> 16) & (BNODES - 1)], t[rec & 0xffffu]);
    }
    __syncthreads();
    // ---- epilogue: fold nodes -> graph slots (once per block, not per record) ----
    int g0 = lb[0];
    int rng = lb[nvalid - 1] - g0 + 1;   // batch sorted -> contiguous graph range
    bool useLDS = (rng <= GSLOTS);
    if (tid < nvalid) {
        float gv = lnode[tid] * ldinv[tid];
        if (s == 0) gv += u[node0 + tid];          // node term folded once
        int gg = lb[tid];
        if (useLDS) {
            atomicAdd(&lgs[gg - g0], gv);
            if (s == 0) atomicAdd(&lgc[gg - g0], 1.0f);
        } else {
            if (gv != 0.f) atomicAdd(gsum + gg, gv);
            if (s == 0) atomicAdd(gcnt + gg, 1.0f);
        }
    }
    __syncthreads();
    if (useLDS) {
        for (int i = tid; i < rng; i += 256) {
            float v = lgs[i];
            if (v != 0.f) atomicAdd(gsum + g0 + i, v);
            if (s == 0) {
                float c = lgc[i];
                if (c != 0.f) atomicAdd(gcnt + g0 + i, c);
            }
        }
    }
}

__global__ __launch_bounds__(256) void final_kernel(
    const float* __restrict__ gsum, const float* __restrict__ gcnt,
    const void* __restrict__ W1l, void* __restrict__ out) {
    int fm = probe_fm_w(W1l);
    int g = blockIdx.x * 256 + threadIdx.x;
    if (g >= N_GRAPHS) return;
    float pooled = gsum[g] / fmaxf(gcnt[g], 1.0f);
    float sg = 1.0f / (1.0f + expf(-pooled));
    if (fm) {
        ((float*)out)[g] = sg;
    } else {
        ((__hip_bfloat16*)out)[g] = __float2bfloat16(sg);
    }
}

extern "C" void kernel_launch(void* const* d_in, const int* in_sizes, int n_in,
                              void* d_out, int out_size, void* d_ws, size_t ws_size,
                              hipStream_t stream) {
    const void* x    = d_in[0];
    const void* W1l  = d_in[1];
    const void* W1r  = d_in[2];
    const void* W2l  = d_in[3];
    const void* W2r  = d_in[4];
    const void* Wfc  = d_in[5];
    const void* ei   = d_in[6];   // [2, E] flat: src then dst
    const void* batc = d_in[7];

    // ws is 256 MiB; ~12 MB used. {bcur,gsum,gcnt} contiguous -> one small
    // memset replaces the serial detect/zero kernel (probes moved in-kernel).
    char* ws = (char*)d_ws;
    int*   bcur = (int*)ws;                               // NBUCK
    float* gsum = (float*)(bcur + NBUCK);                 // N_GRAPHS
    float* gcnt = gsum + N_GRAPHS;                        // N_GRAPHS
    unsigned int* bedges = (unsigned int*)(ws + ((((size_t)(gcnt + N_GRAPHS) - (size_t)ws) + 255) & ~(size_t)255));
    float* p    = (float*)(bedges + (size_t)NBUCK * BCAP);   // (N_NODES+1)*PSTRIDE (+1: sentinel row)
    float* q    = p + (size_t)(N_NODES + 1) * PSTRIDE;       // N_NODES*PSTRIDE
    float* t    = q + (size_t)N_NODES * PSTRIDE;             // N_NODES
    float* u    = t + N_NODES;                               // N_NODES
    float* dinv = u + N_NODES;                               // N_NODES

    hipMemsetAsync(bcur, 0, (NBUCK + 2 * N_GRAPHS) * sizeof(int), stream);
    fusedA_kernel<<<ABLOCKS + PBLOCKS4, 256, 0, stream>>>(
        ei, x, W1l, W1r, bcur, bedges, p, q);
    pullB_kernel<<<NBUCK, 512, 0, stream>>>(bcur, bedges, p, q,
                                            W1l, W2l, W2r, Wfc, t, u, dinv);
    pull2B_kernel<<<NBUCK * SPLIT, 256, 0, stream>>>(bcur, bedges, t, u, dinv, batc, ei, gsum, gcnt);
    final_kernel<<<(N_GRAPHS + 255) / 256, 256, 0, stream>>>(gsum, gcnt, W1l, d_out);
}